// Round 9
// baseline (546.472 us; speedup 1.0000x reference)
//
#include <hip/hip_runtime.h>

// Exphormer attention, fp32 accuracy via split-bf16 MFMA, 16-edge tiles.
// out[dst] += V[src] * exp(clip(sum_d K[src,h,d]*Q[dst,h,d]/4 * Ee[e,h,d], ±5))
// Ee = edge_attr @ We^T + be  (Veltkamp split: hi*hi + hi*lo + lo*hi)
//
// R9: no Ee transpose. MFMA C layout lane(g,q) = Ee[edge 4g+r][dim 16nt+q];
// score reduce is over q (shfl_xor 1,2,4,8 within 16-lane groups) directly.
// K/Q/V gathered in the same layout (per-group 64B, imm-offset batched),
// so the loop has ZERO LDS traffic and no barriers -> occupancy-limited only
// by VGPRs (R8 was LDS-capped at 4 blocks/CU).

typedef __attribute__((ext_vector_type(8))) short bf16x8;   // MFMA A/B frag
typedef __attribute__((ext_vector_type(4))) float f32x4;    // MFMA C/D frag

union frag_u { uint32_t u[4]; uint4 u4; bf16x8 v; };

// pack two f32 (truncated to bf16) into one dword; a -> low half (lower k)
__device__ __forceinline__ uint32_t pack2(float a, float b) {
    return (__float_as_uint(a) >> 16) | (__float_as_uint(b) & 0xffff0000u);
}

// float4 -> 2 hi dwords + 2 lo dwords (bf16 pairs). hi truncate, lo = x-hi exact.
__device__ __forceinline__ void cvt4(float4 v, uint32_t& h0, uint32_t& h1,
                                     uint32_t& l0, uint32_t& l1) {
    float hx = __uint_as_float(__float_as_uint(v.x) & 0xffff0000u);
    float hy = __uint_as_float(__float_as_uint(v.y) & 0xffff0000u);
    float hz = __uint_as_float(__float_as_uint(v.z) & 0xffff0000u);
    float hw = __uint_as_float(__float_as_uint(v.w) & 0xffff0000u);
    h0 = pack2(v.x, v.y);
    h1 = pack2(v.z, v.w);
    l0 = pack2(v.x - hx, v.y - hy);
    l1 = pack2(v.z - hz, v.w - hw);
}

// ---------------- Kernel 1: fused Q/K/V projection ----------------
// Qb[node*64+d]; K/V interleaved: KV[node*128 + d] (K), KV[node*128+64+d] (V)
__global__ __launch_bounds__(256) void proj_kernel(
    const float* __restrict__ x,
    const float* __restrict__ Wq, const float* __restrict__ bq,
    const float* __restrict__ Wk, const float* __restrict__ bk,
    const float* __restrict__ Wv, const float* __restrict__ bv,
    float* __restrict__ Qb, float* __restrict__ KV,
    int n)
{
    __shared__ float WqT[64 * 65];
    __shared__ float WkT[64 * 65];
    __shared__ float WvT[64 * 65];
    __shared__ float xs[4][4][64];

    const int tid  = threadIdx.x;
    const int wave = tid >> 6;
    const int lane = tid & 63;

    #pragma unroll
    for (int k = 0; k < 16; ++k) {
        int idx = tid + k * 256;
        int j = idx >> 6, i = idx & 63;
        WqT[i * 65 + j] = Wq[idx];
        WkT[i * 65 + j] = Wk[idx];
        WvT[i * 65 + j] = Wv[idx];
    }
    const float bqv = bq[lane];
    const float bkv = bk[lane];
    const float bvv = bv[lane];
    __syncthreads();

    for (int blockbase = blockIdx.x * 16; blockbase < n;
         blockbase += gridDim.x * 16) {
        int base = blockbase + wave * 4;
        #pragma unroll
        for (int j = 0; j < 4; ++j) {
            int node = base + j;
            xs[wave][j][lane] = (node < n) ? x[node * 64 + lane] : 0.f;
        }
        __syncthreads();

        float accq[4], acck[4], accv[4];
        #pragma unroll
        for (int j = 0; j < 4; ++j) { accq[j] = bqv; acck[j] = bkv; accv[j] = bvv; }

        #pragma unroll
        for (int f = 0; f < 16; ++f) {
            float wq[4], wk[4], wv[4];
            #pragma unroll
            for (int u = 0; u < 4; ++u) {
                int i = 4 * f + u;
                wq[u] = WqT[i * 65 + lane];
                wk[u] = WkT[i * 65 + lane];
                wv[u] = WvT[i * 65 + lane];
            }
            #pragma unroll
            for (int j = 0; j < 4; ++j) {
                float4 xv = *reinterpret_cast<const float4*>(&xs[wave][j][4 * f]);
                accq[j] = fmaf(xv.x, wq[0], accq[j]);
                accq[j] = fmaf(xv.y, wq[1], accq[j]);
                accq[j] = fmaf(xv.z, wq[2], accq[j]);
                accq[j] = fmaf(xv.w, wq[3], accq[j]);
                acck[j] = fmaf(xv.x, wk[0], acck[j]);
                acck[j] = fmaf(xv.y, wk[1], acck[j]);
                acck[j] = fmaf(xv.z, wk[2], acck[j]);
                acck[j] = fmaf(xv.w, wk[3], acck[j]);
                accv[j] = fmaf(xv.x, wv[0], accv[j]);
                accv[j] = fmaf(xv.y, wv[1], accv[j]);
                accv[j] = fmaf(xv.z, wv[2], accv[j]);
                accv[j] = fmaf(xv.w, wv[3], accv[j]);
            }
        }

        #pragma unroll
        for (int j = 0; j < 4; ++j) {
            int node = base + j;
            if (node < n) {
                Qb[(size_t)node * 64 + lane]       = accq[j];
                KV[(size_t)node * 128 + lane]      = acck[j];
                KV[(size_t)node * 128 + 64 + lane] = accv[j];
            }
        }
        __syncthreads();
    }
}

// ---------------- Kernel 2: 16-edge-tile MFMA attention ----------------
// Fragment layouts (gfx950 16x16x32 bf16, verified R6/R8 passing):
//   A: lane(q=l&15,g=l>>4): row m=q (edge), k = 32ks + 16b + 4g + j
//   B: lane:                col n=q (dim),  k = 32ks + 16b + 4g + j
//   C: lane:                col n=q (dim),  row = 4g + reg (edge)
__global__ __launch_bounds__(256) void edge_kernel(
    const float* __restrict__ ea, const int* __restrict__ ei,
    const float* __restrict__ Qb, const float* __restrict__ KV,
    const float* __restrict__ We, const float* __restrict__ be,
    float* __restrict__ out, int EG)   // EG % 16 == 0
{
    __shared__ uint4 bfragLDS[16][64];   // [(nt*2+ks)*2+hl][lane], 16 KB

    const int tid  = threadIdx.x;
    const int wave = __builtin_amdgcn_readfirstlane(tid >> 6);
    const int lane = tid & 63;
    const int g    = lane >> 4;
    const int q    = lane & 15;

    // ---- build B fragments cooperatively: wave w handles nt = w ----
    {
        const int nt = wave;
        #pragma unroll
        for (int ks = 0; ks < 2; ++ks) {
            frag_u fh, fl;
            #pragma unroll
            for (int b = 0; b < 2; ++b) {
                float4 w4 = *reinterpret_cast<const float4*>(
                    &We[(size_t)(16 * nt + q) * 64 + 32 * ks + 16 * b + 4 * g]);
                cvt4(w4, fh.u[2 * b + 0], fh.u[2 * b + 1],
                         fl.u[2 * b + 0], fl.u[2 * b + 1]);
            }
            bfragLDS[nt * 4 + ks * 2 + 0][lane] = fh.u4;
            bfragLDS[nt * 4 + ks * 2 + 1][lane] = fl.u4;
        }
    }
    float bias4[4];
    #pragma unroll
    for (int nt = 0; nt < 4; ++nt) bias4[nt] = be[16 * nt + q];
    __syncthreads();   // bfragLDS read-only afterwards

    const int nw  = gridDim.x * 4;
    const int wid = blockIdx.x * 4 + wave;

    for (int eb = wid * 16; eb < EG; eb += nw * 16) {   // eb wave-uniform
        // ---- edge indices: uniform address -> s_load ----
        int srcs[16], dsts[16];
        #pragma unroll
        for (int r = 0; r < 16; ++r) {
            srcs[r] = ei[eb + r];
            dsts[r] = ei[EG + eb + r];
        }

        // ---- A fragments from global (row m=q -> edge eb+q) ----
        frag_u Ah[2], Al[2];
        const float* arow = &ea[(size_t)(eb + q) * 64];
        #pragma unroll
        for (int ks = 0; ks < 2; ++ks) {
            #pragma unroll
            for (int b = 0; b < 2; ++b) {
                float4 a4 = *reinterpret_cast<const float4*>(
                    &arow[32 * ks + 16 * b + 4 * g]);
                cvt4(a4, Ah[ks].u[2 * b + 0], Ah[ks].u[2 * b + 1],
                         Al[ks].u[2 * b + 0], Al[ks].u[2 * b + 1]);
            }
        }

        // ---- Ee = ea @ We^T + be via split-bf16 MFMA ----
        f32x4 acc[4];
        #pragma unroll
        for (int nt = 0; nt < 4; ++nt) {
            acc[nt][0] = bias4[nt]; acc[nt][1] = bias4[nt];
            acc[nt][2] = bias4[nt]; acc[nt][3] = bias4[nt];
            #pragma unroll
            for (int ks = 0; ks < 2; ++ks) {
                frag_u bh, bl;
                bh.u4 = bfragLDS[nt * 4 + ks * 2 + 0][lane];
                bl.u4 = bfragLDS[nt * 4 + ks * 2 + 1][lane];
                acc[nt] = __builtin_amdgcn_mfma_f32_16x16x32_bf16(
                              Al[ks].v, bh.v, acc[nt], 0, 0, 0);
                acc[nt] = __builtin_amdgcn_mfma_f32_16x16x32_bf16(
                              Ah[ks].v, bl.v, acc[nt], 0, 0, 0);
                acc[nt] = __builtin_amdgcn_mfma_f32_16x16x32_bf16(
                              Ah[ks].v, bh.v, acc[nt], 0, 0, 0);
            }
        }

        // ---- phase B in C-layout: lane(g,q) owns edge 4g+r, dim 16nt+q ----
        #pragma unroll
        for (int r = 0; r < 4; ++r) {
            // per-lane node ids: select among 4 SGPRs by group g (2 cndmask)
            const int snid = (g & 2) ? ((g & 1) ? srcs[12 + r] : srcs[8 + r])
                                     : ((g & 1) ? srcs[4 + r]  : srcs[r]);
            const int dnid = (g & 2) ? ((g & 1) ? dsts[12 + r] : dsts[8 + r])
                                     : ((g & 1) ? dsts[4 + r]  : dsts[r]);
            const float* kb = KV + (size_t)snid * 128 + q;   // K: +16nt, V: +64+16nt
            const float* qp = Qb + (size_t)dnid * 64 + q;
            float*       ob = out + (size_t)dnid * 64 + q;

            #pragma unroll
            for (int nt = 0; nt < 4; ++nt) {
                const float kv = kb[16 * nt];
                const float qv = qp[16 * nt];
                float t = kv * qv * 0.25f * acc[nt][r];
                t += __shfl_xor(t, 1);          // reduce over q within group
                t += __shfl_xor(t, 2);
                t += __shfl_xor(t, 4);
                t += __shfl_xor(t, 8);
                t = fminf(fmaxf(t, -5.f), 5.f);
                const float s  = __expf(t);
                const float vv = kb[64 + 16 * nt];
                atomicAdd(&ob[16 * nt], vv * s);
            }
        }
    }
}

extern "C" void kernel_launch(void* const* d_in, const int* in_sizes, int n_in,
                              void* d_out, int out_size, void* d_ws, size_t ws_size,
                              hipStream_t stream) {
    const float* x   = (const float*)d_in[0];
    const float* ea  = (const float*)d_in[1];
    const int*   ei  = (const int*)d_in[2];
    const float* Wq  = (const float*)d_in[3];
    const float* bq  = (const float*)d_in[4];
    const float* Wk  = (const float*)d_in[5];
    const float* bk  = (const float*)d_in[6];
    const float* We  = (const float*)d_in[7];
    const float* be  = (const float*)d_in[8];
    const float* Wv  = (const float*)d_in[9];
    const float* bv  = (const float*)d_in[10];
    float* out = (float*)d_out;

    const int n  = in_sizes[0] / 64;   // 50000
    const int EG = in_sizes[1] / 64;   // 1600000 (divisible by 16)

    float* Qb = (float*)d_ws;                 // n*64
    float* KV = Qb + (size_t)n * 64;          // n*128 (K|V interleaved)

    hipMemsetAsync(d_out, 0, (size_t)out_size * sizeof(float), stream);

    const int projGrid = (n + 15) / 16;
    proj_kernel<<<projGrid, 256, 0, stream>>>(x, Wq, bq, Wk, bk, Wv, bv,
                                              Qb, KV, n);

    // 2500 blocks x 4 waves = 10000 waves; 100000 tiles -> 10 tiles/wave exact
    edge_kernel<<<2500, 256, 0, stream>>>(ea, ei, Qb, KV, We, be, out, EG);
}

// Round 10
// 531.459 us; speedup vs baseline: 1.0283x; 1.0283x over previous
//
#include <hip/hip_runtime.h>

// Exphormer attention, fp32 accuracy via split-bf16 MFMA, atomic-free agg.
// out[dst,:] = sum_{e: dst(e)=dst} V[src]*exp(clip(sum_d K*Q/4*Ee, ±5))
// Pipeline: memset(cnt) -> proj(+hist) -> scanA/B/C -> scatter -> agg.
// agg: wave owns 4 dsts (one per 16-lane group); 16-edge MFMA tiles built
// from 4 edge-slots x 4 dsts; register accumulation; plain stores. ZERO
// atomics in the hot loop (R4/R8/R9 all hit the ~240G atomics/s ceiling).

typedef __attribute__((ext_vector_type(8))) short bf16x8;
typedef __attribute__((ext_vector_type(4))) float f32x4;
union frag_u { uint32_t u[4]; uint4 u4; bf16x8 v; };

__device__ __forceinline__ uint32_t pack2(float a, float b) {
    return (__float_as_uint(a) >> 16) | (__float_as_uint(b) & 0xffff0000u);
}
// float4 -> 2 hi dwords + 2 lo dwords (bf16 pairs). hi truncate, lo exact.
__device__ __forceinline__ void cvt4(float4 v, uint32_t& h0, uint32_t& h1,
                                     uint32_t& l0, uint32_t& l1) {
    float hx = __uint_as_float(__float_as_uint(v.x) & 0xffff0000u);
    float hy = __uint_as_float(__float_as_uint(v.y) & 0xffff0000u);
    float hz = __uint_as_float(__float_as_uint(v.z) & 0xffff0000u);
    float hw = __uint_as_float(__float_as_uint(v.w) & 0xffff0000u);
    h0 = pack2(v.x, v.y);
    h1 = pack2(v.z, v.w);
    l0 = pack2(v.x - hx, v.y - hy);
    l1 = pack2(v.z - hz, v.w - hw);
}

// ---------------- Kernel 1: fused Q/K/V projection + dst histogram ----------------
__global__ __launch_bounds__(256) void proj_kernel(
    const float* __restrict__ x,
    const float* __restrict__ Wq, const float* __restrict__ bq,
    const float* __restrict__ Wk, const float* __restrict__ bk,
    const float* __restrict__ Wv, const float* __restrict__ bv,
    const int* __restrict__ ei, int* __restrict__ cnt,
    float* __restrict__ Qb, float* __restrict__ KV,
    int n, int EG)
{
    __shared__ float WqT[64 * 65];
    __shared__ float WkT[64 * 65];
    __shared__ float WvT[64 * 65];
    __shared__ float xs[4][4][64];

    const int tid  = threadIdx.x;
    const int wave = tid >> 6;
    const int lane = tid & 63;

    #pragma unroll
    for (int k = 0; k < 16; ++k) {
        int idx = tid + k * 256;
        int j = idx >> 6, i = idx & 63;
        WqT[i * 65 + j] = Wq[idx];
        WkT[i * 65 + j] = Wk[idx];
        WvT[i * 65 + j] = Wv[idx];
    }
    const float bqv = bq[lane];
    const float bkv = bk[lane];
    const float bvv = bv[lane];
    __syncthreads();

    for (int blockbase = blockIdx.x * 16; blockbase < n;
         blockbase += gridDim.x * 16) {
        int base = blockbase + wave * 4;
        #pragma unroll
        for (int j = 0; j < 4; ++j) {
            int node = base + j;
            xs[wave][j][lane] = (node < n) ? x[node * 64 + lane] : 0.f;
        }
        __syncthreads();

        float accq[4], acck[4], accv[4];
        #pragma unroll
        for (int j = 0; j < 4; ++j) { accq[j] = bqv; acck[j] = bkv; accv[j] = bvv; }

        #pragma unroll
        for (int f = 0; f < 16; ++f) {
            float wq[4], wk[4], wv[4];
            #pragma unroll
            for (int u = 0; u < 4; ++u) {
                int i = 4 * f + u;
                wq[u] = WqT[i * 65 + lane];
                wk[u] = WkT[i * 65 + lane];
                wv[u] = WvT[i * 65 + lane];
            }
            #pragma unroll
            for (int j = 0; j < 4; ++j) {
                float4 xv = *reinterpret_cast<const float4*>(&xs[wave][j][4 * f]);
                accq[j] = fmaf(xv.x, wq[0], accq[j]);
                accq[j] = fmaf(xv.y, wq[1], accq[j]);
                accq[j] = fmaf(xv.z, wq[2], accq[j]);
                accq[j] = fmaf(xv.w, wq[3], accq[j]);
                acck[j] = fmaf(xv.x, wk[0], acck[j]);
                acck[j] = fmaf(xv.y, wk[1], acck[j]);
                acck[j] = fmaf(xv.z, wk[2], acck[j]);
                acck[j] = fmaf(xv.w, wk[3], acck[j]);
                accv[j] = fmaf(xv.x, wv[0], accv[j]);
                accv[j] = fmaf(xv.y, wv[1], accv[j]);
                accv[j] = fmaf(xv.z, wv[2], accv[j]);
                accv[j] = fmaf(xv.w, wv[3], accv[j]);
            }
        }

        #pragma unroll
        for (int j = 0; j < 4; ++j) {
            int node = base + j;
            if (node < n) {
                Qb[(size_t)node * 64 + lane]       = accq[j];
                KV[(size_t)node * 128 + lane]      = acck[j];
                KV[(size_t)node * 128 + 64 + lane] = accv[j];
            }
        }
        __syncthreads();
    }

    // ---- appended dst histogram (hides under other blocks' compute) ----
    {
        const int nt4 = EG >> 2;
        int i  = blockIdx.x * blockDim.x + threadIdx.x;
        int st = gridDim.x * blockDim.x;
        const int4* d4 = reinterpret_cast<const int4*>(ei + EG);
        for (int e = i; e < nt4; e += st) {
            int4 d = d4[e];
            atomicAdd(&cnt[d.x], 1);
            atomicAdd(&cnt[d.y], 1);
            atomicAdd(&cnt[d.z], 1);
            atomicAdd(&cnt[d.w], 1);
        }
    }
}

// ---------------- scan: 3 small kernels ----------------
__global__ __launch_bounds__(256) void scanA_kernel(
    const int* __restrict__ cnt, int* __restrict__ off,
    int* __restrict__ bsum, int n)
{
    __shared__ int s[256];
    const int t = threadIdx.x;
    const int i = blockIdx.x * 256 + t;
    const int v = (i < n) ? cnt[i] : 0;
    s[t] = v;
    __syncthreads();
    for (int d = 1; d < 256; d <<= 1) {
        int u = (t >= d) ? s[t - d] : 0;
        __syncthreads();
        s[t] += u;
        __syncthreads();
    }
    if (i < n) off[i] = s[t] - v;            // exclusive within block
    if (t == 255) bsum[blockIdx.x] = s[255]; // block total
}

__global__ __launch_bounds__(256) void scanB_kernel(int* __restrict__ bsum, int nb)
{
    __shared__ int s[256];
    const int t = threadIdx.x;
    const int v = (t < nb) ? bsum[t] : 0;
    s[t] = v;
    __syncthreads();
    for (int d = 1; d < 256; d <<= 1) {
        int u = (t >= d) ? s[t - d] : 0;
        __syncthreads();
        s[t] += u;
        __syncthreads();
    }
    if (t < nb) bsum[t] = s[t] - v;          // exclusive block offsets
}

__global__ __launch_bounds__(256) void scanC_kernel(
    int* __restrict__ off, const int* __restrict__ bsum,
    int* __restrict__ cursor, int n, int EG)
{
    const int i = blockIdx.x * 256 + threadIdx.x;
    if (i < n) {
        int v = off[i] + bsum[blockIdx.x];
        off[i] = v;
        cursor[i] = v;
    }
    if (i == 0) off[n] = EG;
}

// ---------------- scatter: dst-grouped edge permutation ----------------
__global__ __launch_bounds__(256) void scatter_kernel(
    const int* __restrict__ ei, int* __restrict__ cursor,
    int* __restrict__ perm, int EG)
{
    int i  = blockIdx.x * blockDim.x + threadIdx.x;
    int st = gridDim.x * blockDim.x;
    for (int e = i; e < EG; e += st) {
        int d = ei[EG + e];
        int p = atomicAdd(&cursor[d], 1);
        perm[p] = e;
    }
}

// ---------------- agg: 4 dsts per wave, MFMA tiles, zero atomics ----------------
// A row m (m=0..15) = edge slot (grp=m>>2, slot=m&3) of dst (4*wid + grp).
// C layout: lane(g,q) = row 4g+r (edge slot r of dst group g), col 16nt+q (dim).
__global__ __launch_bounds__(256) void agg_kernel(
    const float* __restrict__ ea, const int* __restrict__ ei,
    const int* __restrict__ off, const int* __restrict__ perm,
    const float* __restrict__ Qb, const float* __restrict__ KV,
    const float* __restrict__ We, const float* __restrict__ be,
    float* __restrict__ out, int n, int EG)
{
    __shared__ uint4 bfragLDS[16][64];   // We fragments, 16 KB
    __shared__ int sidt[4][16];          // per-wave: src of (grp,slot)
    __shared__ int eidt[4][16];          // per-wave: edge id of (grp,slot)

    const int tid  = threadIdx.x;
    const int wave = __builtin_amdgcn_readfirstlane(tid >> 6);
    const int lane = tid & 63;
    const int g    = lane >> 4;
    const int q    = lane & 15;

    {   // build B fragments: wave w handles nt = w
        const int nt = wave;
        #pragma unroll
        for (int ks = 0; ks < 2; ++ks) {
            frag_u fh, fl;
            #pragma unroll
            for (int b = 0; b < 2; ++b) {
                float4 w4 = *reinterpret_cast<const float4*>(
                    &We[(size_t)(16 * nt + q) * 64 + 32 * ks + 16 * b + 4 * g]);
                cvt4(w4, fh.u[2 * b + 0], fh.u[2 * b + 1],
                         fl.u[2 * b + 0], fl.u[2 * b + 1]);
            }
            bfragLDS[nt * 4 + ks * 2 + 0][lane] = fh.u4;
            bfragLDS[nt * 4 + ks * 2 + 1][lane] = fl.u4;
        }
    }
    float bias4[4];
    #pragma unroll
    for (int nt = 0; nt < 4; ++nt) bias4[nt] = be[16 * nt + q];
    __syncthreads();

    const int nw  = gridDim.x * 4;
    const int nd4 = n >> 2;                       // n % 4 == 0

    for (int wid = blockIdx.x * 4 + wave; wid < nd4; wid += nw) {
        const int dbase = wid << 2;
        const int mydst = dbase + g;              // dst owned by my group
        const int j0  = off[mydst];
        const int j1  = off[mydst + 1];
        const int deg = j1 - j0;

        float qreg[4];
        #pragma unroll
        for (int nt = 0; nt < 4; ++nt)
            qreg[nt] = Qb[(size_t)mydst * 64 + 16 * nt + q];

        // table-filling view (lanes 0-15): grp = (lane&15)>>2, slot = lane&3
        const int grp  = (lane & 15) >> 2;
        const int slot = lane & 3;
        const int j0p  = __shfl(j0, grp << 4);
        const int j1p  = __shfl(j1, grp << 4);

        int dm = max(deg, __shfl_xor(deg, 16));
        dm = max(dm, __shfl_xor(dm, 32));
        const int iters = __builtin_amdgcn_readfirstlane((dm + 3) >> 2);

        float macc[4] = {0.f, 0.f, 0.f, 0.f};

        for (int c = 0; c < iters; ++c) {
            if (lane < 16) {
                const int  p     = j0p + 4 * c + slot;
                const bool valid = p < j1p;
                const int  eid   = valid ? perm[p] : 0;
                const int  src   = valid ? ei[eid] : -1;
                eidt[wave][lane] = eid;
                sidt[wave][lane] = src;
            }
            __builtin_amdgcn_wave_barrier();

            // A fragments: row q = edge eidt[q]
            const int eidq = eidt[wave][q];       // broadcast read
            const float* arow = ea + (size_t)eidq * 64;
            frag_u Ah[2], Al[2];
            #pragma unroll
            for (int ks = 0; ks < 2; ++ks) {
                #pragma unroll
                for (int b = 0; b < 2; ++b) {
                    float4 a4 = *reinterpret_cast<const float4*>(
                        &arow[32 * ks + 16 * b + 4 * g]);
                    cvt4(a4, Ah[ks].u[2 * b + 0], Ah[ks].u[2 * b + 1],
                             Al[ks].u[2 * b + 0], Al[ks].u[2 * b + 1]);
                }
            }

            // Ee = ea @ We^T + be (split-bf16, 24 MFMA)
            f32x4 acc[4];
            #pragma unroll
            for (int nt = 0; nt < 4; ++nt) {
                acc[nt][0] = bias4[nt]; acc[nt][1] = bias4[nt];
                acc[nt][2] = bias4[nt]; acc[nt][3] = bias4[nt];
                #pragma unroll
                for (int ks = 0; ks < 2; ++ks) {
                    frag_u bh, bl;
                    bh.u4 = bfragLDS[nt * 4 + ks * 2 + 0][lane];
                    bl.u4 = bfragLDS[nt * 4 + ks * 2 + 1][lane];
                    acc[nt] = __builtin_amdgcn_mfma_f32_16x16x32_bf16(
                                  Al[ks].v, bh.v, acc[nt], 0, 0, 0);
                    acc[nt] = __builtin_amdgcn_mfma_f32_16x16x32_bf16(
                                  Ah[ks].v, bl.v, acc[nt], 0, 0, 0);
                    acc[nt] = __builtin_amdgcn_mfma_f32_16x16x32_bf16(
                                  Ah[ks].v, bh.v, acc[nt], 0, 0, 0);
                }
            }

            // score + register accumulate (no atomics, no Q gather)
            #pragma unroll
            for (int r = 0; r < 4; ++r) {
                const int srcr = sidt[wave][4 * g + r];   // broadcast read
                const float* kb = KV + (size_t)(srcr < 0 ? 0 : srcr) * 128 + q;
                #pragma unroll
                for (int nt = 0; nt < 4; ++nt) {
                    const float kv = kb[16 * nt];
                    const float vv = kb[64 + 16 * nt];
                    float t = kv * qreg[nt] * 0.25f * acc[nt][r];
                    t += __shfl_xor(t, 1);
                    t += __shfl_xor(t, 2);
                    t += __shfl_xor(t, 4);
                    t += __shfl_xor(t, 8);
                    t = fminf(fmaxf(t, -5.f), 5.f);
                    const float s = __expf(t);
                    if (srcr >= 0) macc[nt] = fmaf(vv, s, macc[nt]);
                }
            }
            __builtin_amdgcn_wave_barrier();      // tables rewritten next c
        }

        #pragma unroll
        for (int nt = 0; nt < 4; ++nt)
            out[(size_t)mydst * 64 + 16 * nt + q] = macc[nt];   // plain store
    }
}

extern "C" void kernel_launch(void* const* d_in, const int* in_sizes, int n_in,
                              void* d_out, int out_size, void* d_ws, size_t ws_size,
                              hipStream_t stream) {
    const float* x   = (const float*)d_in[0];
    const float* ea  = (const float*)d_in[1];
    const int*   ei  = (const int*)d_in[2];
    const float* Wq  = (const float*)d_in[3];
    const float* bq  = (const float*)d_in[4];
    const float* Wk  = (const float*)d_in[5];
    const float* bk  = (const float*)d_in[6];
    const float* We  = (const float*)d_in[7];
    const float* be  = (const float*)d_in[8];
    const float* Wv  = (const float*)d_in[9];
    const float* bv  = (const float*)d_in[10];
    float* out = (float*)d_out;

    const int n  = in_sizes[0] / 64;   // 50000
    const int EG = in_sizes[1] / 64;   // 1600000

    // workspace: Qb n*64 f | KV n*128 f | cnt n | off n+1 | cursor n | perm EG | bsum 256
    float* Qb   = (float*)d_ws;
    float* KV   = Qb + (size_t)n * 64;
    int* cnt    = (int*)(KV + (size_t)n * 128);
    int* off    = cnt + n;
    int* cursor = off + n + 1;
    int* perm   = cursor + n;
    int* bsum   = perm + EG;

    hipMemsetAsync(cnt, 0, (size_t)n * sizeof(int), stream);

    const int projGrid = (n + 15) / 16;
    proj_kernel<<<projGrid, 256, 0, stream>>>(x, Wq, bq, Wk, bk, Wv, bv,
                                              ei, cnt, Qb, KV, n, EG);

    const int nb = (n + 255) / 256;    // 196
    scanA_kernel<<<nb, 256, 0, stream>>>(cnt, off, bsum, n);
    scanB_kernel<<<1, 256, 0, stream>>>(bsum, nb);
    scanC_kernel<<<nb, 256, 0, stream>>>(off, bsum, cursor, n, EG);

    scatter_kernel<<<2048, 256, 0, stream>>>(ei, cursor, perm, EG);

    const int aggGrid = (n / 4 + 3) / 4;   // 3125 blocks = 12500 waves
    agg_kernel<<<aggGrid, 256, 0, stream>>>(ea, ei, off, perm,
                                            Qb, KV, We, be, out, n, EG);
}